// Round 3
// baseline (85.836 us; speedup 1.0000x reference)
//
#include <hip/hip_runtime.h>

// STN forward: out[b,c,d,h,w] = trilinear sample of image[b,c] at
// (d,h,w) + ddf[b,:,d,h,w], border-clamped. fp32 in/out.
// image: [B,C,D,H,W], ddf: [B,3,D,H,W], out: [B,C,D,H,W]
//
// R3: VPT=1, batched loads. All 16 corner gathers issued before any use
// (load-arrays -> single consume), __launch_bounds__(256,8) pins VGPR<=64
// so 8 waves/SIMD stay resident. One vmcnt batch per thread.

constexpr int B = 2, C = 2, D = 128, H = 128, W = 128;
constexpr int HW  = H * W;
constexpr int DHW = D * HW;

__global__ __launch_bounds__(256, 8) void stn_fwd_kernel(
    const float* __restrict__ image,
    const float* __restrict__ ddf,
    float* __restrict__ out)
{
    int tid = blockIdx.x * blockDim.x + threadIdx.x;   // 0 .. B*DHW-1
    int b = tid >> 21;            // / DHW
    int s = tid & (DHW - 1);
    int d = s >> 14;
    int r = s & (HW - 1);
    int h = r >> 7;
    int w = r & (W - 1);

    const float* ddfb = ddf + b * 3 * DHW + s;
    float cd = (float)d + ddfb[0 * DHW];
    float ch = (float)h + ddfb[1 * DHW];
    float cw = (float)w + ddfb[2 * DHW];

    // border padding: clamp to [0, dim-1]
    cd = fminf(fmaxf(cd, 0.0f), (float)(D - 1));
    ch = fminf(fmaxf(ch, 0.0f), (float)(H - 1));
    cw = fminf(fmaxf(cw, 0.0f), (float)(W - 1));

    float d0f = floorf(cd), h0f = floorf(ch), w0f = floorf(cw);
    float fd = cd - d0f, fh = ch - h0f, fw = cw - w0f;

    int d0 = (int)d0f, h0 = (int)h0f, w0 = (int)w0f;
    int d1 = min(d0 + 1, D - 1);
    int h1 = min(h0 + 1, H - 1);
    int w1 = min(w0 + 1, W - 1);

    // 8 corner offsets (shared by both channels)
    int off[8];
    off[0] = d0 * HW + h0 * W + w0;
    off[1] = d0 * HW + h0 * W + w1;
    off[2] = d0 * HW + h1 * W + w0;
    off[3] = d0 * HW + h1 * W + w1;
    off[4] = d1 * HW + h0 * W + w0;
    off[5] = d1 * HW + h0 * W + w1;
    off[6] = d1 * HW + h1 * W + w0;
    off[7] = d1 * HW + h1 * W + w1;

    const float* img0 = image + (b * C + 0) * DHW;
    const float* img1 = image + (b * C + 1) * DHW;

    // Issue ALL 16 gathers before any use -> one vmcnt batch.
    float a0[8], a1[8];
#pragma unroll
    for (int i = 0; i < 8; ++i) a0[i] = img0[off[i]];
#pragma unroll
    for (int i = 0; i < 8; ++i) a1[i] = img1[off[i]];

    float gd = 1.0f - fd, gh = 1.0f - fh, gw = 1.0f - fw;
    float wt[8];
    wt[0] = gd * gh * gw;
    wt[1] = gd * gh * fw;
    wt[2] = gd * fh * gw;
    wt[3] = gd * fh * fw;
    wt[4] = fd * gh * gw;
    wt[5] = fd * gh * fw;
    wt[6] = fd * fh * gw;
    wt[7] = fd * fh * fw;

    float v0 = 0.0f, v1 = 0.0f;
#pragma unroll
    for (int i = 0; i < 8; ++i) v0 += a0[i] * wt[i];
#pragma unroll
    for (int i = 0; i < 8; ++i) v1 += a1[i] * wt[i];

    out[(b * C + 0) * DHW + s] = v0;
    out[(b * C + 1) * DHW + s] = v1;
}

extern "C" void kernel_launch(void* const* d_in, const int* in_sizes, int n_in,
                              void* d_out, int out_size, void* d_ws, size_t ws_size,
                              hipStream_t stream) {
    const float* image = (const float*)d_in[0];
    const float* ddf   = (const float*)d_in[1];
    float* out = (float*)d_out;

    int total = B * DHW;
    int block = 256;
    int grid  = (total + block - 1) / block;  // 16384 blocks
    stn_fwd_kernel<<<grid, block, 0, stream>>>(image, ddf, out);
}

// Round 4
// 56.480 us; speedup vs baseline: 1.5198x; 1.5198x over previous
//
#include <hip/hip_runtime.h>

// STN forward, LDS-tiled. out[b,c,d,h,w] = trilinear sample of image[b,c] at
// (d,h,w)+ddf[b,:,d,h,w], border-clamped. fp32.
// Theory: direct gathers are TA/L1-transaction-bound (per-lane random rows).
// Fix: stage a (T+9)^3 halo region per 16^3 tile in LDS (both channels),
// gather from LDS. Rare |ddf|>4 lanes fall back to global loads.

constexpr int B = 2, C = 2, D = 128, H = 128, W = 128;
constexpr int HW  = H * W;
constexpr int DHW = D * HW;
constexpr int TD = 16, TH = 16, TW = 16;     // output tile
constexpr int HALO = 4;
constexpr int RD = TD + 2 * HALO + 1;        // 25 (d extent)
constexpr int RH = TH + 2 * HALO + 1;        // 25 (h extent)
constexpr int RWP = 28;                      // padded w extent (7 granules)
constexpr int CHF = RD * RH * RWP;           // 17500 floats / channel
constexpr int CHG = CHF / 4;                 // 4375 granules / channel
constexpr int TOTG = 2 * CHG;                // 8750 granules
constexpr int NT = 1024;                     // threads / block
constexpr int NSTG = (TOTG + NT - 1) / NT;   // 9 staging granules / thread

__global__ __launch_bounds__(NT, 4) void stn_kernel(
    const float* __restrict__ image,
    const float* __restrict__ ddf,
    float* __restrict__ out)
{
    __shared__ float smem[2 * CHF];          // 140000 B

    int blk = blockIdx.x;
    int b   = blk >> 9;                      // 512 tiles per batch
    int tb  = blk & 511;
    int tdi = tb >> 6, thi = (tb >> 3) & 7, twi = tb & 7;
    int t0d = tdi * TD, t0h = thi * TH, t0w = twi * TW;
    int lo_d = max(t0d - HALO, 0), lo_h = max(t0h - HALO, 0), lo_w = max(t0w - HALO, 0);
    int hi_d = min(t0d + TD + HALO, D - 1);
    int hi_h = min(t0h + TH + HALO, H - 1);
    int hi_w = min(t0w + TW + HALO, W - 1);

    const float* imgb = image + (size_t)b * C * DHW;
    int tid = threadIdx.x;

    // ---- stage: issue ALL region loads (coalesced float4) ----
    float4 stg[NSTG];
#pragma unroll
    for (int i = 0; i < NSTG; ++i) {
        int g = tid + i * NT; if (g >= TOTG) g = TOTG - 1;
        int ch  = (g >= CHG) ? 1 : 0;
        int gc  = g - ch * CHG;
        int row = gc / 7;
        int rw  = (gc - row * 7) * 4;
        int rd  = row / RH;
        int rh  = row - rd * RH;
        int gd = min(lo_d + rd, D - 1);
        int gh = min(lo_h + rh, H - 1);
        int gw = min(lo_w + rw, W - 4);
        stg[i] = *reinterpret_cast<const float4*>(imgb + ch * DHW + gd * HW + gh * W + gw);
    }

    // ---- ddf loads (overlap staging latency) ----
    int dl = tid >> 6;               // 0..15
    int hl = (tid >> 2) & 15;        // 0..15
    int wq = tid & 3;                // 0..3
    int d  = t0d + dl, h = t0h + hl;
    int w4 = t0w + wq * 4;
    int sidx = d * HW + h * W + w4;
    const float* dp = ddf + (size_t)b * 3 * DHW + sidx;
    float4 fdd = *reinterpret_cast<const float4*>(dp);
    float4 fdh = *reinterpret_cast<const float4*>(dp + DHW);
    float4 fdw = *reinterpret_cast<const float4*>(dp + 2 * DHW);

    // ---- write staged data to LDS ----
#pragma unroll
    for (int i = 0; i < NSTG; ++i) {
        int g = tid + i * NT; if (g >= TOTG) g = TOTG - 1;
        *reinterpret_cast<float4*>(&smem[g * 4]) = stg[i];
    }
    __syncthreads();

    // ---- compute 4 voxels / thread ----
    const float ddk[4] = {fdd.x, fdd.y, fdd.z, fdd.w};
    const float dhk[4] = {fdh.x, fdh.y, fdh.z, fdh.w};
    const float dwk[4] = {fdw.x, fdw.y, fdw.z, fdw.w};
    float accA[4], accB[4];

#pragma unroll
    for (int k = 0; k < 4; ++k) {
        float cd = fminf(fmaxf((float)d + ddk[k], 0.0f), (float)(D - 1));
        float ch = fminf(fmaxf((float)h + dhk[k], 0.0f), (float)(H - 1));
        float cw = fminf(fmaxf((float)(w4 + k) + dwk[k], 0.0f), (float)(W - 1));

        float d0f = floorf(cd), h0f = floorf(ch), w0f = floorf(cw);
        float fd = cd - d0f, fh = ch - h0f, fw = cw - w0f;
        int d0 = (int)d0f, h0 = (int)h0f, w0 = (int)w0f;
        int d1 = min(d0 + 1, D - 1);
        int h1 = min(h0 + 1, H - 1);
        int w1 = min(w0 + 1, W - 1);

        bool ok = (d0 >= lo_d) & (d1 <= hi_d) & (h0 >= lo_h) & (h1 <= hi_h)
                & (w0 >= lo_w) & (w1 <= hi_w);

        float gd = 1.0f - fd, gh = 1.0f - fh, gw = 1.0f - fw;
        float w00 = gh * gw, w01 = gh * fw, w10 = fh * gw, w11 = fh * fw;

        // LDS indices (garbage if !ok — discarded; LDS OOB reads don't fault)
        int ld0 = d0 - lo_d, ld1 = d1 - lo_d;
        int lh0 = h0 - lo_h, lh1 = h1 - lo_h;
        int lw0 = w0 - lo_w, lw1 = w1 - lo_w;
        int i00 = (ld0 * RH + lh0) * RWP;
        int i01 = (ld0 * RH + lh1) * RWP;
        int i10 = (ld1 * RH + lh0) * RWP;
        int i11 = (ld1 * RH + lh1) * RWP;

        float pA0 = smem[i00 + lw0] * w00 + smem[i00 + lw1] * w01
                  + smem[i01 + lw0] * w10 + smem[i01 + lw1] * w11;
        float pA1 = smem[i10 + lw0] * w00 + smem[i10 + lw1] * w01
                  + smem[i11 + lw0] * w10 + smem[i11 + lw1] * w11;
        float pB0 = smem[CHF + i00 + lw0] * w00 + smem[CHF + i00 + lw1] * w01
                  + smem[CHF + i01 + lw0] * w10 + smem[CHF + i01 + lw1] * w11;
        float pB1 = smem[CHF + i10 + lw0] * w00 + smem[CHF + i10 + lw1] * w01
                  + smem[CHF + i11 + lw0] * w10 + smem[CHF + i11 + lw1] * w11;
        float vA = gd * pA0 + fd * pA1;
        float vB = gd * pB0 + fd * pB1;

        if (!ok) {  // rare (|ddf|>4): exact global fallback
            int o00 = d0 * HW + h0 * W, o01 = d0 * HW + h1 * W;
            int o10 = d1 * HW + h0 * W, o11 = d1 * HW + h1 * W;
            const float* iA = imgb;
            const float* iB = imgb + DHW;
            float qA0 = iA[o00 + w0] * w00 + iA[o00 + w1] * w01
                      + iA[o01 + w0] * w10 + iA[o01 + w1] * w11;
            float qA1 = iA[o10 + w0] * w00 + iA[o10 + w1] * w01
                      + iA[o11 + w0] * w10 + iA[o11 + w1] * w11;
            float qB0 = iB[o00 + w0] * w00 + iB[o00 + w1] * w01
                      + iB[o01 + w0] * w10 + iB[o01 + w1] * w11;
            float qB1 = iB[o10 + w0] * w00 + iB[o10 + w1] * w01
                      + iB[o11 + w0] * w10 + iB[o11 + w1] * w11;
            vA = gd * qA0 + fd * qA1;
            vB = gd * qB0 + fd * qB1;
        }
        accA[k] = vA;
        accB[k] = vB;
    }

    float4* oA = reinterpret_cast<float4*>(out + ((size_t)b * C + 0) * DHW + sidx);
    float4* oB = reinterpret_cast<float4*>(out + ((size_t)b * C + 1) * DHW + sidx);
    *oA = make_float4(accA[0], accA[1], accA[2], accA[3]);
    *oB = make_float4(accB[0], accB[1], accB[2], accB[3]);
}

extern "C" void kernel_launch(void* const* d_in, const int* in_sizes, int n_in,
                              void* d_out, int out_size, void* d_ws, size_t ws_size,
                              hipStream_t stream) {
    const float* image = (const float*)d_in[0];
    const float* ddf   = (const float*)d_in[1];
    float* out = (float*)d_out;

    int grid = B * 512;   // 8x8x8 tiles of 16^3 per batch
    stn_kernel<<<grid, NT, 0, stream>>>(image, ddf, out);
}